// Round 3
// baseline (359.708 us; speedup 1.0000x reference)
//
#include <hip/hip_runtime.h>
#include <stddef.h>

#define NB 4
#define NH 4
#define NN 2048
#define DIN 128
#define HD 32
#define NBH 16

constexpr float SLOPE = 0.2f;
constexpr float LC = 7.2134752044448170f; // log2(e) / TEMP

// ---------------- Kernel A: Wh[bh][n][o] = sum_i h[b][n][i] * W[h][i][o] ----
__global__ __launch_bounds__(256) void kWh(const float* __restrict__ hg,
                                           const float* __restrict__ Wg,
                                           float* __restrict__ Wh)
{
    __shared__ float Wl[DIN*HD];
    __shared__ float Hl[8][DIN];
    const int t = threadIdx.x;
    const int bh = blockIdx.x >> 4;
    const int tile = blockIdx.x & 15;
    const int b = bh >> 2, hh = bh & 3;
    for (int i = t; i < DIN*HD; i += 256) Wl[i] = Wg[hh*DIN*HD + i];
    const int o = t & 31, r = t >> 5;
    for (int it = 0; it < 16; ++it){
        const int nb = tile*128 + it*8;
        __syncthreads();
        {
            const float4* src = (const float4*)&hg[((size_t)b*NN + nb)*DIN];
            ((float4*)Hl)[t] = src[t];
        }
        __syncthreads();
        float acc = 0.f;
        #pragma unroll 8
        for (int i = 0; i < DIN; ++i) acc = fmaf(Hl[r][i], Wl[i*HD+o], acc);
        Wh[((size_t)bh*NN + nb + r)*HD + o] = acc;
    }
}

// ---------------- Kernel A2: s_src, s_dst, max over m of s_dst --------------
__global__ __launch_bounds__(256) void kScore(const float* __restrict__ Wh,
                                              const float* __restrict__ ag,
                                              float* __restrict__ sSrc,
                                              float* __restrict__ sDst,
                                              float* __restrict__ maxDst)
{
    __shared__ float al[64];
    __shared__ float wm[4];
    const int t = threadIdx.x;
    const int bh = blockIdx.x;
    const int hh = bh & 3;
    if (t < 64) al[t] = ag[hh*64 + t];
    __syncthreads();
    float lmax = -3.4e38f;
    for (int rr = 0; rr < 8; ++rr){
        const int n = rr*256 + t;
        const float4* wr = (const float4*)&Wh[((size_t)bh*NN + n)*HD];
        float ss = 0.f, sd = 0.f;
        #pragma unroll
        for (int q = 0; q < 8; ++q){
            float4 w = wr[q];
            ss += w.x*al[q*4+0] + w.y*al[q*4+1] + w.z*al[q*4+2] + w.w*al[q*4+3];
            sd += w.x*al[32+q*4+0] + w.y*al[32+q*4+1] + w.z*al[32+q*4+2] + w.w*al[32+q*4+3];
        }
        sSrc[bh*NN+n] = ss; sDst[bh*NN+n] = sd;
        lmax = fmaxf(lmax, sd);
    }
    #pragma unroll
    for (int off = 32; off > 0; off >>= 1) lmax = fmaxf(lmax, __shfl_down(lmax, off));
    if ((t & 63) == 0) wm[t >> 6] = lmax;
    __syncthreads();
    if (t == 0) maxDst[bh] = fmaxf(fmaxf(wm[0], wm[1]), fmaxf(wm[2], wm[3]));
}

// ---------------- Kernel B: Z + PV (fused, known row-max) -------------------
__global__ __launch_bounds__(256) void kAttn(const float* __restrict__ Wh,
                                             const float* __restrict__ sSrc,
                                             const float* __restrict__ sDst,
                                             const float* __restrict__ maxDst,
                                             float* __restrict__ invZ,
                                             float* __restrict__ hc)
{
    __shared__ float Wt[128*HD];
    __shared__ float sd[128];
    __shared__ float red[4*64*33];
    __shared__ float zred[256];
    const int t = threadIdx.x;
    const int bh = blockIdx.x >> 5;
    const int n0 = (blockIdx.x & 31) * 64;
    const int c = t >> 6, l = t & 63;
    const int n = n0 + l;
    const float ssrc = sSrc[bh*NN + n];
    const float q0 = ssrc + maxDst[bh];
    const float rmaxLC = fmaxf(q0, SLOPE*q0) * LC;
    float acc[32];
    #pragma unroll
    for (int o = 0; o < 32; ++o) acc[o] = 0.f;
    float Zp = 0.f;
    const size_t whbase = (size_t)bh*NN*HD;
    for (int mt = 0; mt < 16; ++mt){
        const int mb = mt*128;
        __syncthreads();
        {
            const float4* src = (const float4*)&Wh[whbase + (size_t)mb*HD];
            float4* dst = (float4*)Wt;
            for (int i = t; i < 128*HD/4; i += 256) dst[i] = src[i];
            if (t < 128) sd[t] = sDst[bh*NN + mb + t];
        }
        __syncthreads();
        const int mlo = c*32;
        #pragma unroll 4
        for (int mm = 0; mm < 32; ++mm){
            const int ml = mlo + mm;
            const float x = ssrc + sd[ml];
            const float lr = fmaxf(x, SLOPE*x);
            const float p = exp2f(fmaf(lr, LC, -rmaxLC));
            Zp += p;
            const float4* wr = (const float4*)&Wt[ml*HD];
            #pragma unroll
            for (int qq = 0; qq < 8; ++qq){
                const float4 w = wr[qq];
                acc[qq*4+0] = fmaf(p, w.x, acc[qq*4+0]);
                acc[qq*4+1] = fmaf(p, w.y, acc[qq*4+1]);
                acc[qq*4+2] = fmaf(p, w.z, acc[qq*4+2]);
                acc[qq*4+3] = fmaf(p, w.w, acc[qq*4+3]);
            }
        }
    }
    float* my = &red[(c*64 + l)*33];
    #pragma unroll
    for (int o = 0; o < 32; ++o) my[o] = acc[o];
    zred[c*64 + l] = Zp;
    __syncthreads();
    const int b = bh >> 2, hh = bh & 3;
    for (int idx = t; idx < 2048; idx += 256){
        const int r = idx >> 5, o = idx & 31;
        const float s = red[r*33+o] + red[(64+r)*33+o] + red[(128+r)*33+o] + red[(192+r)*33+o];
        const float Zt = zred[r] + zred[64+r] + zred[128+r] + zred[192+r];
        const float iz = 1.0f / Zt;
        const int nn2 = n0 + r;
        hc[((size_t)b*NN + nn2)*128 + hh*HD + o] = s * iz;
        if (o == 0) invZ[bh*NN + nn2] = iz;
    }
}

// ---------------- Kernel C: alpha_mean -> out1 (f32) ------------------------
__global__ __launch_bounds__(256) void kAlpha(const float* __restrict__ sSrc,
                                              const float* __restrict__ sDst,
                                              const float* __restrict__ maxDst,
                                              const float* __restrict__ invZ,
                                              float* __restrict__ out1)
{
    __shared__ float sdl[4][NN];
    const int t = threadIdx.x;
    const int b = blockIdx.x >> 7;
    const int n0 = (blockIdx.x & 127) * 16;
    for (int i = t; i < 4*NN; i += 256)
        sdl[i >> 11][i & (NN-1)] = sDst[(size_t)(b*4 + (i>>11))*NN + (i & (NN-1))];
    __syncthreads();
    for (int rr = 0; rr < 16; ++rr){
        const int n = n0 + rr;
        float ssrcv[4], rmv[4], cf[4];
        #pragma unroll
        for (int hh = 0; hh < 4; ++hh){
            const int bhn = (b*4 + hh)*NN + n;
            const float ss = sSrc[bhn];
            const float q = ss + maxDst[b*4+hh];
            ssrcv[hh] = ss;
            rmv[hh] = fmaxf(q, SLOPE*q)*LC;
            cf[hh] = 0.25f * invZ[bhn];
        }
        float* orow = out1 + ((size_t)b*NN + n)*NN;
        for (int mb = 0; mb < NN; mb += 256){
            const int m = mb + t;
            float v = 0.f;
            #pragma unroll
            for (int hh = 0; hh < 4; ++hh){
                const float x = ssrcv[hh] + sdl[hh][m];
                const float lr = fmaxf(x, SLOPE*x);
                v += cf[hh] * exp2f(fmaf(lr, LC, -rmv[hh]));
            }
            orow[m] = v;
        }
    }
}

// ---------------- Kernel D: merge GEMM + bias -> out0 (f32) -----------------
__global__ __launch_bounds__(256) void kMerge(const float* __restrict__ hc,
                                              const float* __restrict__ mw,
                                              const float* __restrict__ mbv,
                                              float* __restrict__ out0)
{
    __shared__ float mwT[128*129];
    __shared__ float hcl[2][128];
    const int t = threadIdx.x;
    for (int i = t; i < 128*128; i += 256){
        const int j = i >> 7, k = i & 127;
        mwT[k*129 + j] = mw[i];
    }
    const int j = t & 127;
    const float bj = mbv[j];
    const int rhalf = t >> 7;
    for (int it = 0; it < 32; ++it){
        const int rloc = it*2 + rhalf;
        const size_t row = (size_t)blockIdx.x*64 + rloc;
        __syncthreads();
        hcl[t >> 7][t & 127] = hc[((size_t)blockIdx.x*64 + it*2 + (t>>7))*128 + (t & 127)];
        __syncthreads();
        float a = bj;
        #pragma unroll 8
        for (int k = 0; k < 128; ++k) a = fmaf(hcl[rhalf][k], mwT[k*129 + j], a);
        out0[row*128 + j] = a;
    }
}

extern "C" void kernel_launch(void* const* d_in, const int* in_sizes, int n_in,
                              void* d_out, int out_size, void* d_ws, size_t ws_size,
                              hipStream_t stream)
{
    const float* hg  = (const float*)d_in[0];
    const float* Wg  = (const float*)d_in[1];
    const float* ag  = (const float*)d_in[2];
    const float* mw  = (const float*)d_in[3];
    const float* mbv = (const float*)d_in[4];
    float* out0 = (float*)d_out;
    float* out1 = out0 + (size_t)NB*NN*128;

    float* ws     = (float*)d_ws;
    float* Wh     = ws;                   // 1,048,576 f32
    float* sSrc   = Wh + 1048576;         //    32,768
    float* sDst   = sSrc + 32768;         //    32,768
    float* maxDst = sDst + 32768;         //        16
    float* invZ   = maxDst + 16;          //    32,768
    float* hc     = invZ + 32768;         // 1,048,576   (total ~8.8 MB)

    hipLaunchKernelGGL(kWh,    dim3(NBH*16), dim3(256), 0, stream, hg, Wg, Wh);
    hipLaunchKernelGGL(kScore, dim3(NBH),    dim3(256), 0, stream, Wh, ag, sSrc, sDst, maxDst);
    hipLaunchKernelGGL(kAttn,  dim3(NBH*32), dim3(256), 0, stream, Wh, sSrc, sDst, maxDst, invZ, hc);
    hipLaunchKernelGGL(kAlpha, dim3(NB*128), dim3(256), 0, stream, sSrc, sDst, maxDst, invZ, out1);
    hipLaunchKernelGGL(kMerge, dim3(128),    dim3(256), 0, stream, hc, mw, mbv, out0);
}

// Round 4
// 169.319 us; speedup vs baseline: 2.1244x; 2.1244x over previous
//
#include <hip/hip_runtime.h>
#include <stddef.h>

#define NN 2048
#define DIN 128
#define HD 32

typedef __attribute__((ext_vector_type(8))) short short8;
typedef __attribute__((ext_vector_type(4))) float f32x4;

constexpr float SLOPE = 0.2f;
constexpr float LC = 7.2134752044448170f; // log2(e)/TEMP

__device__ __forceinline__ unsigned int pack_rne(float a, float b){
    unsigned int xa = __float_as_uint(a), xb = __float_as_uint(b);
    unsigned int ra = (xa + 0x7fffu + ((xa >> 16) & 1u)) >> 16;
    unsigned int rb = (xb + 0x7fffu + ((xb >> 16) & 1u)) >> 16;
    return ra | (rb << 16);
}

// ---------------- kWh: Wh[bh][n][o] = sum_i h[b][n][i] * W[h][i][o] (f32) ---
__global__ __launch_bounds__(256) void kWh(const float* __restrict__ hg,
                                           const float* __restrict__ Wg,
                                           float* __restrict__ Wh)
{
    __shared__ float Wl[DIN*HD];
    __shared__ float Hl[8][DIN+4];   // +4 pad: bank = (4r+i)%32, conflict-free
    const int t = threadIdx.x;
    const int bh = blockIdx.x >> 5;
    const int tile = blockIdx.x & 31;
    const int b = bh >> 2, hh = bh & 3;
    for (int i = t; i < DIN*HD; i += 256) Wl[i] = Wg[hh*DIN*HD + i];
    const int o = t & 31, r = t >> 5;
    for (int it = 0; it < 8; ++it){
        const int nb = tile*64 + it*8;
        __syncthreads();
        {
            const float4 v = *(const float4*)&hg[((size_t)b*NN + nb + r)*DIN + o*4];
            *(float4*)&Hl[r][o*4] = v;
        }
        __syncthreads();
        float acc = 0.f;
        #pragma unroll 8
        for (int i = 0; i < DIN; ++i) acc = fmaf(Hl[r][i], Wl[i*HD+o], acc);
        Wh[((size_t)bh*NN + nb + r)*HD + o] = acc;
    }
}

// ---------------- kScore: s_src, s_dst, per-segment max partials ------------
__global__ __launch_bounds__(256) void kScore(const float* __restrict__ Wh,
                                              const float* __restrict__ ag,
                                              float* __restrict__ sSrc,
                                              float* __restrict__ sDst,
                                              float* __restrict__ maxPart)
{
    __shared__ float al[64];
    __shared__ float wred[4];
    const int t = threadIdx.x;
    const int bh = blockIdx.x >> 3, seg = blockIdx.x & 7;
    const int hh = bh & 3;
    if (t < 64) al[t] = ag[hh*64 + t];
    __syncthreads();
    const int n = seg*256 + t;
    const float4* wr = (const float4*)&Wh[((size_t)bh*NN + n)*HD];
    float ss = 0.f, sd = 0.f;
    #pragma unroll
    for (int q = 0; q < 8; ++q){
        float4 w = wr[q];
        ss += w.x*al[q*4+0] + w.y*al[q*4+1] + w.z*al[q*4+2] + w.w*al[q*4+3];
        sd += w.x*al[32+q*4+0] + w.y*al[32+q*4+1] + w.z*al[32+q*4+2] + w.w*al[32+q*4+3];
    }
    sSrc[bh*NN+n] = ss; sDst[bh*NN+n] = sd;
    float lmax = sd;
    #pragma unroll
    for (int off = 32; off > 0; off >>= 1) lmax = fmaxf(lmax, __shfl_down(lmax, off));
    if ((t & 63) == 0) wred[t >> 6] = lmax;
    __syncthreads();
    if (t == 0) maxPart[bh*8 + seg] = fmaxf(fmaxf(wred[0], wred[1]), fmaxf(wred[2], wred[3]));
}

// ---------------- kAttnM: fused softmax (known max) + PV via MFMA -----------
// block = 4 waves x 16 rows = 64 rows; grid = 16 bh x 32 tiles.
// A-frag: P generated in regs: A[row=lane&15][k=(lane>>4)*8+j]
// B-frag: WtT[o][m] bf16 in LDS -> 8 consecutive m = one b128 per tile
__global__ __launch_bounds__(256) void kAttnM(const float* __restrict__ Wh,
                                              const float* __restrict__ sSrc,
                                              const float* __restrict__ sDst,
                                              const float* __restrict__ maxPart,
                                              float* __restrict__ invZ,
                                              unsigned short* __restrict__ hcb)
{
    __shared__ unsigned short WtT[32][136];  // [o][m-tile 128], pad 8 keeps 16B align
    __shared__ float sdl[128];               // LC * s_dst for this m-tile
    const int t = threadIdx.x;
    const int wv = t >> 6, lane = t & 63;
    const int q = lane >> 4, c = lane & 15;
    const int bh = blockIdx.x >> 5;
    const int n0 = (blockIdx.x & 31)*64 + wv*16;
    const int b = bh >> 2, hh = bh & 3;
    float mx = maxPart[bh*8];
    #pragma unroll
    for (int i = 1; i < 8; ++i) mx = fmaxf(mx, maxPart[bh*8 + i]);
    const float ssrc = sSrc[bh*NN + n0 + c];
    const float q0 = ssrc + mx;
    const float R = fmaxf(q0, SLOPE*q0) * LC;
    const float a1 = ssrc*LC - R;
    const float a2 = SLOPE*LC*ssrc - R;
    f32x4 acc0 = {0.f,0.f,0.f,0.f}, acc1 = {0.f,0.f,0.f,0.f};
    float Zp = 0.f;
    const size_t whbase = (size_t)bh*NN*HD;
    for (int mt = 0; mt < 16; ++mt){
        const int mb = mt*128;
        __syncthreads();
        // stage Wh tile (128m x 32o f32) -> WtT[o][m] bf16, rows paired for b32 writes
        #pragma unroll
        for (int ii = 0; ii < 2; ++ii){
            const int idx = t + 256*ii;             // 0..511
            const int c4 = idx & 7, rp = idx >> 3;  // rp 0..63 (row pair)
            const float4 v0 = *(const float4*)&Wh[whbase + (size_t)(mb + 2*rp)*HD + c4*4];
            const float4 v1 = *(const float4*)&Wh[whbase + (size_t)(mb + 2*rp + 1)*HD + c4*4];
            const unsigned int* b0 = (const unsigned int*)&v0;
            const unsigned int* b1 = (const unsigned int*)&v1;
            #pragma unroll
            for (int k = 0; k < 4; ++k){
                unsigned int xa = b0[k], xb = b1[k];
                unsigned int pk = ((xa + 0x7fffu + ((xa>>16)&1u)) >> 16)
                                | (((xb + 0x7fffu + ((xb>>16)&1u)) >> 16) << 16);
                *(unsigned int*)&WtT[c4*4 + k][2*rp] = pk;
            }
        }
        if (t < 128) sdl[t] = LC * sDst[bh*NN + mb + t];
        __syncthreads();
        #pragma unroll
        for (int ks = 0; ks < 4; ++ks){
            const int m8 = ks*32 + q*8;
            float p[8];
            #pragma unroll
            for (int j = 0; j < 8; ++j){
                const float u = sdl[m8 + j];
                p[j] = exp2f(fmaxf(a1 + u, fmaf(SLOPE, u, a2)));
                Zp += p[j];
            }
            short8 aF;
            #pragma unroll
            for (int j = 0; j < 8; j += 2){
                ((unsigned int*)&aF)[j>>1] = (__float_as_uint(p[j]) >> 16)
                                           | (__float_as_uint(p[j+1]) & 0xffff0000u);
            }
            const short8 bF0 = *(const short8*)&WtT[c][m8];
            const short8 bF1 = *(const short8*)&WtT[16 + c][m8];
            acc0 = __builtin_amdgcn_mfma_f32_16x16x32_bf16(aF, bF0, acc0, 0, 0, 0);
            acc1 = __builtin_amdgcn_mfma_f32_16x16x32_bf16(aF, bF1, acc1, 0, 0, 0);
        }
    }
    // Z: sum the 4 quad-lanes of each row (lanes c, c+16, c+32, c+48)
    Zp += __shfl_xor(Zp, 16);
    Zp += __shfl_xor(Zp, 32);
    const float iz = 1.0f / Zp;          // Z for row n0 + c
    if (q == 0) invZ[bh*NN + n0 + c] = iz;
    // epilogue: C/D layout col=lane&15, row=q*4+reg
    #pragma unroll
    for (int reg = 0; reg < 4; ++reg){
        const int row = q*4 + reg;
        const float izr = __shfl(iz, row);
        const size_t base = ((size_t)b*NN + n0 + row)*128 + hh*32;
        hcb[base + c]      = (unsigned short)((pack_rne(acc0[reg]*izr, 0.f)) & 0xffffu);
        hcb[base + 16 + c] = (unsigned short)((pack_rne(acc1[reg]*izr, 0.f)) & 0xffffu);
    }
}

// ---------------- kAlpha: alpha.mean over heads -> out1 (f32) ---------------
__global__ __launch_bounds__(256) void kAlpha(const float* __restrict__ sSrc,
                                              const float* __restrict__ sDst,
                                              const float* __restrict__ maxPart,
                                              const float* __restrict__ invZ,
                                              float* __restrict__ out1)
{
    __shared__ float sdl[4][NN];     // LC * s_dst, 32 KB
    const int t = threadIdx.x;
    const int b = blockIdx.x >> 9;
    const int n0 = (blockIdx.x & 511) * 4;
    for (int i = t; i < 4*NN; i += 256)
        sdl[i >> 11][i & (NN-1)] = LC * sDst[(size_t)(b*4 + (i>>11))*NN + (i & (NN-1))];
    __syncthreads();
    float a1[4][4], a2[4][4], cf[4][4];   // [row][head]
    #pragma unroll
    for (int hh = 0; hh < 4; ++hh){
        float mx = maxPart[(b*4+hh)*8];
        #pragma unroll
        for (int i = 1; i < 8; ++i) mx = fmaxf(mx, maxPart[(b*4+hh)*8 + i]);
        #pragma unroll
        for (int rr = 0; rr < 4; ++rr){
            const int bhn = (b*4+hh)*NN + n0 + rr;
            const float ss = sSrc[bhn];
            const float q0 = ss + mx;
            const float R = fmaxf(q0, SLOPE*q0)*LC;
            a1[rr][hh] = ss*LC - R;
            a2[rr][hh] = SLOPE*LC*ss - R;
            cf[rr][hh] = 0.25f * invZ[bhn];
        }
    }
    for (int mb = 0; mb < NN; mb += 256){
        const int m = mb + t;
        const float u0 = sdl[0][m], u1 = sdl[1][m], u2 = sdl[2][m], u3 = sdl[3][m];
        #pragma unroll
        for (int rr = 0; rr < 4; ++rr){
            float v;
            v  = cf[rr][0]*exp2f(fmaxf(a1[rr][0]+u0, fmaf(SLOPE, u0, a2[rr][0])));
            v += cf[rr][1]*exp2f(fmaxf(a1[rr][1]+u1, fmaf(SLOPE, u1, a2[rr][1])));
            v += cf[rr][2]*exp2f(fmaxf(a1[rr][2]+u2, fmaf(SLOPE, u2, a2[rr][2])));
            v += cf[rr][3]*exp2f(fmaxf(a1[rr][3]+u3, fmaf(SLOPE, u3, a2[rr][3])));
            out1[((size_t)b*NN + n0 + rr)*NN + m] = v;
        }
    }
}

// ---------------- kMergeM: out0 = hcb(bf16) @ mw^T(bf16) + bias via MFMA ----
// block = 4 waves x 16 rows = 64 rows; grid = 128. B[k][col] = mw[col][k] (no transpose!)
__global__ __launch_bounds__(256) void kMergeM(const unsigned short* __restrict__ hcb,
                                               const float* __restrict__ mw,
                                               const float* __restrict__ mbv,
                                               float* __restrict__ out0)
{
    __shared__ unsigned short mwb[128][136];
    const int t = threadIdx.x;
    const int wv = t >> 6, lane = t & 63;
    const int q = lane >> 4, c = lane & 15;
    for (int i = t; i < 128*64; i += 256){
        const int j = i >> 6, k2 = i & 63;
        const float2 v = *(const float2*)&mw[j*128 + k2*2];
        *(unsigned int*)&mwb[j][k2*2] = pack_rne(v.x, v.y);
    }
    __syncthreads();
    const int row0 = blockIdx.x*64 + wv*16;
    f32x4 acc[8];
    #pragma unroll
    for (int ot = 0; ot < 8; ++ot) acc[ot] = (f32x4){0.f,0.f,0.f,0.f};
    #pragma unroll
    for (int ks = 0; ks < 4; ++ks){
        const short8 aF = *(const short8*)&hcb[((size_t)row0 + c)*128 + ks*32 + q*8];
        #pragma unroll
        for (int ot = 0; ot < 8; ++ot){
            const short8 bF = *(const short8*)&mwb[ot*16 + c][ks*32 + q*8];
            acc[ot] = __builtin_amdgcn_mfma_f32_16x16x32_bf16(aF, bF, acc[ot], 0, 0, 0);
        }
    }
    #pragma unroll
    for (int ot = 0; ot < 8; ++ot){
        const int col = ot*16 + c;
        const float bias = mbv[col];
        #pragma unroll
        for (int reg = 0; reg < 4; ++reg){
            const size_t row = (size_t)row0 + q*4 + reg;
            out0[row*128 + col] = acc[ot][reg] + bias;
        }
    }
}

extern "C" void kernel_launch(void* const* d_in, const int* in_sizes, int n_in,
                              void* d_out, int out_size, void* d_ws, size_t ws_size,
                              hipStream_t stream)
{
    const float* hg  = (const float*)d_in[0];
    const float* Wg  = (const float*)d_in[1];
    const float* ag  = (const float*)d_in[2];
    const float* mw  = (const float*)d_in[3];
    const float* mbv = (const float*)d_in[4];
    float* out0 = (float*)d_out;
    float* out1 = out0 + (size_t)4*NN*128;

    float* ws     = (float*)d_ws;
    float* Wh     = ws;                       // 1,048,576 f32
    float* sSrc   = Wh + 1048576;             //    32,768
    float* sDst   = sSrc + 32768;             //    32,768
    float* maxPart= sDst + 32768;             //       128
    float* invZ   = maxPart + 128;            //    32,768
    unsigned short* hcb = (unsigned short*)(invZ + 32768);  // 1,048,576 bf16

    hipLaunchKernelGGL(kWh,    dim3(512),  dim3(256), 0, stream, hg, Wg, Wh);
    hipLaunchKernelGGL(kScore, dim3(128),  dim3(256), 0, stream, Wh, ag, sSrc, sDst, maxPart);
    hipLaunchKernelGGL(kAttnM, dim3(512),  dim3(256), 0, stream, Wh, sSrc, sDst, maxPart, invZ, hcb);
    hipLaunchKernelGGL(kAlpha, dim3(2048), dim3(256), 0, stream, sSrc, sDst, maxPart, invZ, out1);
    hipLaunchKernelGGL(kMergeM,dim3(128),  dim3(256), 0, stream, hcb, mw, mbv, out0);
}